// Round 9
// baseline (632.505 us; speedup 1.0000x reference)
//
#include <hip/hip_runtime.h>

#define NT   128
#define SS   512
#define LDSW 132                       // f32 row stride: 16B-aligned, bank-spread

typedef short bf16x8 __attribute__((ext_vector_type(8)));   // 8 bf16 in 4 VGPRs
typedef int   i32x4  __attribute__((ext_vector_type(4)));
typedef float f32x4  __attribute__((ext_vector_type(4)));

union FR { i32x4 i; bf16x8 h; };

// pack two f32 -> one dword of two bf16 (truncation)
__device__ __forceinline__ int pk_trunc(float hi, float lo) {
    return (int)__builtin_amdgcn_perm(__float_as_uint(hi), __float_as_uint(lo), 0x07060302u);
}
// pack with round-to-nearest-even (used for the one-time expT conversion)
__device__ __forceinline__ int pk_rne(float hi, float lo) {
    unsigned a = __float_as_uint(hi); a += 0x7FFFu + ((a >> 16) & 1u);
    unsigned b = __float_as_uint(lo); b += 0x7FFFu + ((b >> 16) & 1u);
    return (int)__builtin_amdgcn_perm(a, b, 0x07060302u);
}

__global__ void zero_out_kernel(float* out) { out[0] = 0.0f; }

__global__ __launch_bounds__(64, 1) void crf_fwd_kernel(
    const float* __restrict__ emissions,        // [B, S, NT] f32
    const int* __restrict__ tags,               // [B, S]
    const unsigned char* __restrict__ mask,     // [B, S]
    const float* __restrict__ trans,            // [NT, NT] f32
    float* __restrict__ out)                    // [1] f32
{
    const int l  = threadIdx.x;                 // 0..63
    const int li = l & 15;                      // batch-in-group / n-index
    const int q  = l >> 4;                      // lane quad 0..3
    const int b0 = blockIdx.x * 16;             // 16 batches per wave

    __shared__ float lds[2][16 * LDSW];

    // ---- gold score (lane l: batch li, t = q + 4k) ----
    float gold = 0.0f;
    {
        const int*           tg = tags + (size_t)(b0 + li) * SS;
        const unsigned char* mk = mask + (size_t)(b0 + li) * SS;
        const float*         em = emissions + (size_t)(b0 + li) * SS * NT;
        for (int t = q; t < SS; t += 4) {
            int   tv = tg[t];
            float m  = mk[t] ? 1.0f : 0.0f;
            float a  = em[(size_t)t * NT + tv];
            if (t > 0) a += trans[tg[t - 1] * NT + tv];
            gold += a * m;
        }
    }

    // ---- B fragments: expT, B[k = kt*32+q*8+j][n = nt*16+li] ----
    bf16x8 Bf[4][8];
    #pragma unroll
    for (int kt = 0; kt < 4; kt++) {
        #pragma unroll
        for (int nt = 0; nt < 8; nt++) {
            float ev[8];
            #pragma unroll
            for (int j = 0; j < 8; j++)
                ev[j] = __expf(trans[(size_t)(kt * 32 + q * 8 + j) * NT + nt * 16 + li]);
            FR u;
            u.i = (i32x4){ pk_rne(ev[1], ev[0]), pk_rne(ev[3], ev[2]),
                           pk_rne(ev[5], ev[4]), pk_rne(ev[7], ev[6]) };
            Bf[kt][nt] = u.h;
        }
    }

    // ---- A0: p̂0 = exp(e0), A[m=li][k=kt*32+q*8+j] ----
    const float* emL = emissions + (size_t)(b0 + li) * SS * NT;   // batch li
    bf16x8 Af[4];
    #pragma unroll
    for (int kt = 0; kt < 4; kt++) {
        f32x4 x0 = *(const f32x4*)(emL + kt * 32 + q * 8);
        f32x4 x1 = *(const f32x4*)(emL + kt * 32 + q * 8 + 4);
        float e0 = __expf(x0.x), e1 = __expf(x0.y), e2 = __expf(x0.z), e3 = __expf(x0.w);
        float e4 = __expf(x1.x), e5 = __expf(x1.y), e6 = __expf(x1.z), e7 = __expf(x1.w);
        FR u;
        u.i = (i32x4){ pk_trunc(e1, e0), pk_trunc(e3, e2),
                       pk_trunc(e5, e4), pk_trunc(e7, e6) };
        Af[kt] = u.h;
    }

    // ---- emission pipeline: RE=e_{t+1}(even slots), RA=e_{t+2}; fac 1 ahead ----
    f32x4 RE[8], RA[8], facO[8], facE[8];
    float S = 0.0f, Kcur = 0.0f, KfO = 0.0f, KfE = 0.0f;
    {
        f32x4 R1[8];
        #pragma unroll
        for (int h = 0; h < 8; h++) {
            int off = (h >> 1) * 32 + q * 8 + (h & 1) * 4;
            R1[h] = *(const f32x4*)(emL + (size_t)1 * NT + off);
            RE[h] = *(const f32x4*)(emL + (size_t)2 * NT + off);
            RA[h] = *(const f32x4*)(emL + (size_t)3 * NT + off);
        }
        #pragma unroll
        for (int h = 0; h < 8; h++) {
            f32x4 r = R1[h];
            facO[h] = (f32x4){ __expf(r.x), __expf(r.y), __expf(r.z), __expf(r.w) };
        }
        KfO = 0.0f;
    }

    const float L2E = 1.44269504088896f;
    f32x4 V[8];                                  // alpha exp-values, A layout

    #pragma unroll 1
    for (int t = 1; t < SS; t += 2) {
        // =============== odd sub-step t (LDS parity 0) ===============
        {
            f32x4 D[8];
            #pragma unroll
            for (int nt = 0; nt < 8; nt++) D[nt] = (f32x4){0.f, 0.f, 0.f, 0.f};
            #pragma unroll
            for (int kt = 0; kt < 4; kt++)
                #pragma unroll
                for (int nt = 0; nt < 8; nt++)
                    D[nt] = __builtin_amdgcn_mfma_f32_16x16x32_bf16(Af[kt], Bf[kt][nt], D[nt], 0, 0, 0);

            float* Lw = &lds[0][(q * 4) * LDSW + li];        // rows 4q+r, col nt*16+li
            #pragma unroll
            for (int nt = 0; nt < 8; nt++) {
                Lw[0 * LDSW + nt * 16] = D[nt].x;
                Lw[1 * LDSW + nt * 16] = D[nt].y;
                Lw[2 * LDSW + nt * 16] = D[nt].z;
                Lw[3 * LDSW + nt * 16] = D[nt].w;
            }

            // fac for t+1 from RE = e_{t+1}; reload RE <- e_{t+3}
            #pragma unroll
            for (int h = 0; h < 8; h++) {
                f32x4 r = RE[h];
                facE[h].x = __builtin_amdgcn_exp2f(fmaf(r.x, L2E, -Kcur));
                facE[h].y = __builtin_amdgcn_exp2f(fmaf(r.y, L2E, -Kcur));
                facE[h].z = __builtin_amdgcn_exp2f(fmaf(r.z, L2E, -Kcur));
                facE[h].w = __builtin_amdgcn_exp2f(fmaf(r.w, L2E, -Kcur));
            }
            KfE = Kcur;
            int t3 = t + 3; if (t3 > SS - 1) t3 = SS - 1;
            #pragma unroll
            for (int h = 0; h < 8; h++) {
                int off = (h >> 1) * 32 + q * 8 + (h & 1) * 4;
                RE[h] = *(const f32x4*)(emL + (size_t)t3 * NT + off);
            }

            // read u back (A layout), apply fac
            const float* Lr = &lds[0][li * LDSW + q * 8];
            #pragma unroll
            for (int kt = 0; kt < 4; kt++) {
                f32x4 u0 = *(const f32x4*)(Lr + kt * 32);
                f32x4 u1 = *(const f32x4*)(Lr + kt * 32 + 4);
                V[kt * 2 + 0] = u0 * facO[kt * 2 + 0];
                V[kt * 2 + 1] = u1 * facO[kt * 2 + 1];
            }
            S += KfO;

            // pack V -> A frags (truncation)
            #pragma unroll
            for (int kt = 0; kt < 4; kt++) {
                f32x4 a = V[kt * 2 + 0], b = V[kt * 2 + 1];
                FR u;
                u.i = (i32x4){ pk_trunc(a.y, a.x), pk_trunc(a.w, a.z),
                               pk_trunc(b.y, b.x), pk_trunc(b.w, b.z) };
                Af[kt] = u.h;
            }
        }
        // =============== even sub-step t+1 (LDS parity 1) ===============
        if (t + 1 < SS) {
            f32x4 D[8];
            #pragma unroll
            for (int nt = 0; nt < 8; nt++) D[nt] = (f32x4){0.f, 0.f, 0.f, 0.f};
            #pragma unroll
            for (int kt = 0; kt < 4; kt++)
                #pragma unroll
                for (int nt = 0; nt < 8; nt++)
                    D[nt] = __builtin_amdgcn_mfma_f32_16x16x32_bf16(Af[kt], Bf[kt][nt], D[nt], 0, 0, 0);

            float* Lw = &lds[1][(q * 4) * LDSW + li];
            #pragma unroll
            for (int nt = 0; nt < 8; nt++) {
                Lw[0 * LDSW + nt * 16] = D[nt].x;
                Lw[1 * LDSW + nt * 16] = D[nt].y;
                Lw[2 * LDSW + nt * 16] = D[nt].z;
                Lw[3 * LDSW + nt * 16] = D[nt].w;
            }

            // fac for t+2 from RA = e_{t+2}; reload RA <- e_{t+4}
            #pragma unroll
            for (int h = 0; h < 8; h++) {
                f32x4 r = RA[h];
                facO[h].x = __builtin_amdgcn_exp2f(fmaf(r.x, L2E, -Kcur));
                facO[h].y = __builtin_amdgcn_exp2f(fmaf(r.y, L2E, -Kcur));
                facO[h].z = __builtin_amdgcn_exp2f(fmaf(r.z, L2E, -Kcur));
                facO[h].w = __builtin_amdgcn_exp2f(fmaf(r.w, L2E, -Kcur));
            }
            KfO = Kcur;
            int t4 = t + 4; if (t4 > SS - 1) t4 = SS - 1;
            #pragma unroll
            for (int h = 0; h < 8; h++) {
                int off = (h >> 1) * 32 + q * 8 + (h & 1) * 4;
                RA[h] = *(const f32x4*)(emL + (size_t)t4 * NT + off);
            }

            const float* Lr = &lds[1][li * LDSW + q * 8];
            #pragma unroll
            for (int kt = 0; kt < 4; kt++) {
                f32x4 u0 = *(const f32x4*)(Lr + kt * 32);
                f32x4 u1 = *(const f32x4*)(Lr + kt * 32 + 4);
                V[kt * 2 + 0] = u0 * facE[kt * 2 + 0];
                V[kt * 2 + 1] = u1 * facE[kt * 2 + 1];
            }
            S += KfE;

            #pragma unroll
            for (int kt = 0; kt < 4; kt++) {
                f32x4 a = V[kt * 2 + 0], b = V[kt * 2 + 1];
                FR u;
                u.i = (i32x4){ pk_trunc(a.y, a.x), pk_trunc(a.w, a.z),
                               pk_trunc(b.y, b.x), pk_trunc(b.w, b.z) };
                Af[kt] = u.h;
            }

            // stale per-batch rescale exponent (off-chain, every 2 steps)
            f32x4 mv = V[0];
            #pragma unroll
            for (int h = 1; h < 8; h++) mv = __builtin_elementwise_max(mv, V[h]);
            float m = fmaxf(fmaxf(mv.x, mv.y), fmaxf(mv.z, mv.w));
            m = fmaxf(m, __shfl_xor(m, 16));
            m = fmaxf(m, __shfl_xor(m, 32));
            Kcur = (float)((int)((__float_as_uint(m) >> 23) & 255u) - 127);
        }
    }

    // ---- epilogue: P_b = S_b·ln2 + log Σ_j V ; total partition − gold ----
    {
        f32x4 sv = V[0];
        #pragma unroll
        for (int h = 1; h < 8; h++) sv = sv + V[h];
        float sb = (sv.x + sv.y) + (sv.z + sv.w);
        sb += __shfl_xor(sb, 16);
        sb += __shfl_xor(sb, 32);
        float P = S * 0.69314718055994531f + __logf(sb);
        float part = (l < 16) ? P : 0.0f;
        #pragma unroll
        for (int o = 32; o > 0; o >>= 1) {
            part += __shfl_xor(part, o);
            gold += __shfl_xor(gold, o);
        }
        if (l == 0) atomicAdd(out, part - gold);
    }
}

extern "C" void kernel_launch(void* const* d_in, const int* in_sizes, int n_in,
                              void* d_out, int out_size, void* d_ws, size_t ws_size,
                              hipStream_t stream) {
    const float*         emissions = (const float*)d_in[0];
    const int*           tags      = (const int*)d_in[1];
    const unsigned char* mask      = (const unsigned char*)d_in[2];
    const float*         trans     = (const float*)d_in[3];
    float*               out       = (float*)d_out;

    zero_out_kernel<<<1, 1, 0, stream>>>(out);
    crf_fwd_kernel<<<16, 64, 0, stream>>>(emissions, tags, mask, trans, out);
}

// Round 10
// 240.183 us; speedup vs baseline: 2.6334x; 2.6334x over previous
//
#include <hip/hip_runtime.h>

#define NT 128
#define SS 512
#define PW 132                         // padded per-wave column stride (floats)

typedef float f32x2 __attribute__((ext_vector_type(2)));

__device__ __forceinline__ float rdlane(float v, int lane) {
    return __int_as_float(__builtin_amdgcn_readlane(__float_as_int(v), lane));
}
__device__ __forceinline__ int fexp_of(float x) {
    return (int)((__float_as_uint(x) >> 23) & 0xFFu) - 127;
}
// barrier draining only LDS ops — global prefetches stay in flight
__device__ __forceinline__ void lds_barrier() {
    asm volatile("s_waitcnt lgkmcnt(0)\n\ts_barrier" ::: "memory");
}

__global__ void zero_out_kernel(float* out) { out[0] = 0.0f; }

__global__ __launch_bounds__(256, 1) void crf_fwd_kernel(
    const float* __restrict__ emissions,        // [B, S, NT] f32
    const int* __restrict__ tags,               // [B, S]
    const unsigned char* __restrict__ mask,     // [B, S]
    const float* __restrict__ trans,            // [NT, NT] f32
    float* __restrict__ out)                    // [1] f32
{
    const int b   = blockIdx.x;                 // one batch per block
    const int tid = threadIdx.x;                // 0..255
    const int l   = tid & 63;
    const int w   = tid >> 6;                   // wave 0..3: rows/states 32w..32w+31
    const int st  = (w << 5) + (l & 31);        // owned state (dup on lane pairs)

    __shared__ float pbuf[2][4 * PW];           // [parity][wave*PW + col]
    __shared__ int   kbuf[4];
    __shared__ float redf[4];
    __shared__ float redg[4];

    const float*         emB = emissions + (size_t)b * SS * NT;
    const int*           tgB = tags + b * SS;
    const unsigned char* mkB = mask + b * SS;

    // ---- gold score fully hoisted off the recursion ----
    float gold = 0.0f;
    for (int t = tid; t < SS; t += 256) {
        int tg   = tgB[t];
        float mk = mkB[t] ? 1.0f : 0.0f;
        float a  = emB[(size_t)t * NT + tg];
        if (t > 0) a += trans[tgB[t - 1] * NT + tg];
        gold += a * mk;
    }

    // ---- expT: own 32 rows, cols {l, l+64} packed -> 64 VGPRs ----
    f32x2 eTr[32];
    #pragma unroll
    for (int r = 0; r < 32; r++) {
        const float* row = trans + (size_t)((w << 5) + r) * NT;
        f32x2 v; v.x = __expf(row[l]); v.y = __expf(row[l + 64]);
        eTr[r] = v;
    }

    // ---- init: true alpha_j = p̂ * 2^S * e^{M0} (S global) ----
    float a0 = emB[st];
    {
        float v = a0;                            // max within 32-lane halves
        #pragma unroll
        for (int o = 16; o > 0; o >>= 1) v = fmaxf(v, __shfl_xor(v, o));
        if (l == 0) redf[w] = v;
    }
    __syncthreads();
    const float M0 = fmaxf(fmaxf(redf[0], redf[1]), fmaxf(redf[2], redf[3]));

    float p = __expf(a0 - M0);                  // p̂ for state st (duplicated)
    float S = 0.0f;
    int K = 0, kv_own = 0;

    // ---- emission pipeline: loads 4 deep, exp 2 steps off-chain ----
    float ex_o = __expf(emB[(size_t)1 * NT + st]);   // exp(e_1)
    float ex_e = __expf(emB[(size_t)2 * NT + st]);   // exp(e_2)
    float pd_o = emB[(size_t)3 * NT + st];
    float pd_e = emB[(size_t)4 * NT + st];

    // matvec over own 32 rows + 4-way partial combine; 1 lgkm barrier
    auto matvec = [&](int q, bool kw) -> float {
        f32x2 A0 = {0.f,0.f}, A1 = {0.f,0.f}, A2 = {0.f,0.f}, A3 = {0.f,0.f};
        #pragma unroll
        for (int r = 0; r < 32; r += 4) {
            float q0 = rdlane(p, r + 0);
            float q1 = rdlane(p, r + 1);
            float q2 = rdlane(p, r + 2);
            float q3 = rdlane(p, r + 3);
            f32x2 b0 = {q0, q0}, b1 = {q1, q1}, b2 = {q2, q2}, b3 = {q3, q3};
            A0 = __builtin_elementwise_fma(b0, eTr[r + 0], A0);
            A1 = __builtin_elementwise_fma(b1, eTr[r + 1], A1);
            A2 = __builtin_elementwise_fma(b2, eTr[r + 2], A2);
            A3 = __builtin_elementwise_fma(b3, eTr[r + 3], A3);
        }
        f32x2 s2 = (A0 + A1) + (A2 + A3);       // {partial col l, partial col l+64}
        pbuf[q][w * PW + l]      = s2.x;
        pbuf[q][w * PW + l + 64] = s2.y;
        if (kw && l == 0) kbuf[w] = kv_own;     // rides the barrier
        lds_barrier();                          // lgkm-only: vmcnt untouched
        return (pbuf[q][0 * PW + st] + pbuf[q][1 * PW + st]) +
               (pbuf[q][2 * PW + st] + pbuf[q][3 * PW + st]);
    };
    auto rot = [&](int t, float& pd, float& ex) {
        float nr = pd;
        int tn = t + 4; if (tn > SS - 1) tn = SS - 1;
        pd = emB[(size_t)tn * NT + st];
        ex = __expf(nr);
    };

    // ---- forward recursion: groups of 4 steps; rescale at sub-step 0 ----
    #pragma unroll 1
    for (int t = 1; t < SS; t += 4) {
        {   // sub 0 (parity 1): apply K, propose next kv (swizzles 1x/group)
            float sn = matvec(1, false) * ex_o;
            p = ldexpf(sn, -K);
            S += (float)K;
            int kv = fexp_of(p);
            #pragma unroll
            for (int o = 16; o > 0; o >>= 1) kv = max(kv, __shfl_xor(kv, o));
            kv_own = kv;
            rot(t, pd_o, ex_o);
        }
        if (t + 1 < SS) {   // sub 1 (parity 0): K exchange piggyback
            float sn = matvec(0, true) * ex_e;
            int k0 = kbuf[0], k1 = kbuf[1], k2 = kbuf[2], k3 = kbuf[3];
            K = max(max(k0, k1), max(k2, k3));
            p = sn;
            rot(t + 1, pd_e, ex_e);
        }
        if (t + 2 < SS) { p = matvec(1, false) * ex_o; rot(t + 2, pd_o, ex_o); }
        if (t + 3 < SS) { p = matvec(0, false) * ex_e; rot(t + 3, pd_e, ex_e); }
    }

    // ---- epilogue: partition = M0 + S*ln2 + log Σ p̂ ; reduce gold ----
    {
        float sw = (l < 32) ? p : 0.0f;         // states duplicated on lane pairs
        float g  = gold;
        #pragma unroll
        for (int o = 32; o > 0; o >>= 1) {
            sw += __shfl_xor(sw, o);
            g  += __shfl_xor(g, o);
        }
        if (l == 0) { redf[w] = sw; redg[w] = g; }
    }
    __syncthreads();
    if (tid == 0) {
        float tot  = (redf[0] + redf[1]) + (redf[2] + redf[3]);
        float part = M0 + S * 0.69314718055994531f + __logf(tot);
        float gt   = (redg[0] + redg[1]) + (redg[2] + redg[3]);
        atomicAdd(out, part - gt);
    }
}

extern "C" void kernel_launch(void* const* d_in, const int* in_sizes, int n_in,
                              void* d_out, int out_size, void* d_ws, size_t ws_size,
                              hipStream_t stream) {
    const float*         emissions = (const float*)d_in[0];
    const int*           tags      = (const int*)d_in[1];
    const unsigned char* mask      = (const unsigned char*)d_in[2];
    const float*         trans     = (const float*)d_in[3];
    float*               out       = (float*)d_out;

    zero_out_kernel<<<1, 1, 0, stream>>>(out);
    crf_fwd_kernel<<<256, 256, 0, stream>>>(emissions, tags, mask, trans, out);
}